// Round 1
// baseline (751.682 us; speedup 1.0000x reference)
//
#include <hip/hip_runtime.h>
#include <hip/hip_bf16.h>
#include <stdint.h>
#include <stddef.h>

// Problem: C[4096,11008] = X[4096,4096] @ dequant(Wpacked)^T
//   W[o,i] = (sext4(nibble(o,i)) - zero[o, i/128]) * scale[o, i/128]
// Strategy R1: pre-dequant W->bf16 and X->bf16 into d_ws (if it fits),
// then m97-style 128x128x64 bf16 MFMA GEMM with global_load_lds staging
// and XOR-swizzled LDS (swizzle implemented by permuting per-lane global
// source addresses, since global_load_lds dest is wave-uniform base + lane*16).

#define M_TOK 4096
#define K_IN  4096
#define N_OUT 11008
#define QGROUPS 32

typedef __bf16 bf8 __attribute__((ext_vector_type(8)));
typedef short  s8v __attribute__((ext_vector_type(8)));
typedef float  f4v __attribute__((ext_vector_type(4)));

__device__ __forceinline__ unsigned short f2bf(float f) {
  union { float f; unsigned u; } v; v.f = f;
  unsigned r = v.u + 0x7FFFu + ((v.u >> 16) & 1u);  // RNE
  return (unsigned short)(r >> 16);
}

__device__ __forceinline__ void gload16(const void* g, void* l) {
  __builtin_amdgcn_global_load_lds(
      (__attribute__((address_space(1))) void*)(g),
      (__attribute__((address_space(3))) void*)(l),
      16, 0, 0);
}

// ---------------- prepass: X fp32 -> bf16 ----------------
__global__ __launch_bounds__(256) void cvt_x_kernel(const float* __restrict__ x,
                                                    unsigned short* __restrict__ xb) {
  size_t t = (size_t)blockIdx.x * 256 + threadIdx.x;
  const float4* src = (const float4*)x + t * 2;
  float4 a = src[0], b = src[1];
  union { unsigned short u[8]; s8v v; } o;
  o.u[0] = f2bf(a.x); o.u[1] = f2bf(a.y); o.u[2] = f2bf(a.z); o.u[3] = f2bf(a.w);
  o.u[4] = f2bf(b.x); o.u[5] = f2bf(b.y); o.u[6] = f2bf(b.z); o.u[7] = f2bf(b.w);
  ((s8v*)xb)[t] = o.v;
}

// ---------------- prepass: packed int4 -> bf16 W[N][K] ----------------
__device__ __forceinline__ void deq_pair(int b, float s, float zf, unsigned short* dst) {
  int lo = (b << 28) >> 28;           // sign-extended low nibble  (elem 2p)
  int hi = (b << 24) >> 28;           // sign-extended high nibble (elem 2p+1)
  dst[0] = f2bf(((float)lo - zf) * s);
  dst[1] = f2bf(((float)hi - zf) * s);
}

__global__ __launch_bounds__(256) void deq_w_kernel(const int* __restrict__ wp,
                                                    const float* __restrict__ wsc,
                                                    const int* __restrict__ wz,
                                                    unsigned short* __restrict__ wb) {
  size_t t = (size_t)blockIdx.x * 256 + threadIdx.x;
  size_t e0 = t * 8;                       // first weight element (row-major [N][K])
  int o = (int)(e0 >> 12);                 // /4096
  int k = (int)(e0 & 4095);
  int g = k >> 7;                          // /128
  float s  = wsc[o * QGROUPS + g];
  float zf = (float)wz[o * QGROUPS + g];
  int4 pk = ((const int4*)wp)[t];          // 4 packed bytes = 8 weights
  union { unsigned short u[8]; s8v v; } r;
  deq_pair(pk.x, s, zf, &r.u[0]);
  deq_pair(pk.y, s, zf, &r.u[2]);
  deq_pair(pk.z, s, zf, &r.u[4]);
  deq_pair(pk.w, s, zf, &r.u[6]);
  ((s8v*)wb)[t] = r.v;
}

// ---------------- GEMM ----------------
// Tile: BM=128, BN=128, BK=64. 256 threads = 4 waves (2x2), each wave 64x64
// = 4x4 frags of mfma_f32_16x16x32_bf16.
// LDS layout: tile stored as 16B "units"; unit(row, kb) lives at index
//   row*8 + (kb ^ (row&7)); kb = k-unit (8 bf16) 0..7 within BK=64.
// Frag read (A or B, [rows][K] k-contiguous): lane reads unit (row0+lane&15,
//   ks*4 + lane>>4) -> ds_read_b128, 2-way bank aliasing only (free, m136).
template <bool PRE>
__global__ __launch_bounds__(256, 2) void gemm_kernel(
    const unsigned short* __restrict__ Ab,   // PRE: bf16 X [M][K]
    const unsigned short* __restrict__ Bb,   // PRE: bf16 W [N][K]
    const float* __restrict__ X,             // fused path
    const int* __restrict__ WP,
    const float* __restrict__ WS,
    const int* __restrict__ WZ,
    float* __restrict__ C) {
  __shared__ __align__(16) short As[128 * 64];
  __shared__ __align__(16) short Bs[128 * 64];

  const int tid  = threadIdx.x;
  const int lane = tid & 63;
  const int wid  = tid >> 6;
  const int n0 = blockIdx.x * 128;
  const int m0 = blockIdx.y * 128;
  const int wm = (wid >> 1) * 64;
  const int wn = (wid & 1) * 64;
  const int quad = lane >> 4;
  const int lrow = lane & 15;
  const int sw   = lrow & 7;

  f4v acc[4][4];
#pragma unroll
  for (int i = 0; i < 4; ++i)
#pragma unroll
    for (int j = 0; j < 4; ++j) acc[i][j] = (f4v){0.f, 0.f, 0.f, 0.f};

  // staging lane roles
  const int srl = lane >> 3;               // row within 8-row slab (PRE)
  const int skb = (lane & 7) ^ srl;        // swizzled k-unit (PRE)
  const int frow  = tid >> 1;              // fused: row 0..127
  const int fhalf = tid & 1;               // fused: k-half

  for (int kt = 0; kt < K_IN / 64; ++kt) {
    const int k0 = kt * 64;
    __syncthreads();  // protect LDS from previous iter's readers
    if (PRE) {
#pragma unroll
      for (int j = 0; j < 4; ++j) {
        int slab = wid * 4 + j;            // 0..15, 8 rows each
        int row  = slab * 8 + srl;
        gload16(Ab + (size_t)(m0 + row) * K_IN + k0 + skb * 8,
                (char*)As + slab * 1024);
        gload16(Bb + (size_t)(n0 + row) * K_IN + k0 + skb * 8,
                (char*)Bs + slab * 1024);
      }
    } else {
      const int g = k0 >> 7;               // BK=64 fits inside one 128-group
      float s  = WS[(n0 + frow) * QGROUPS + g];
      float zf = (float)WZ[(n0 + frow) * QGROUPS + g];
#pragma unroll
      for (int j = 0; j < 4; ++j) {
        int kb = fhalf * 4 + j;
        int unit = frow * 8 + (kb ^ (frow & 7));
        // A: fp32 -> bf16
        const float4* xs = (const float4*)(X + (size_t)(m0 + frow) * K_IN + k0 + kb * 8);
        float4 a = xs[0], b = xs[1];
        union { unsigned short u[8]; s8v v; } oa;
        oa.u[0] = f2bf(a.x); oa.u[1] = f2bf(a.y); oa.u[2] = f2bf(a.z); oa.u[3] = f2bf(a.w);
        oa.u[4] = f2bf(b.x); oa.u[5] = f2bf(b.y); oa.u[6] = f2bf(b.z); oa.u[7] = f2bf(b.w);
        *(s8v*)(As + unit * 8) = oa.v;
        // B: unpack + dequant -> bf16
        const int4 pk = *(const int4*)(WP + ((size_t)(n0 + frow) * K_IN + k0 + kb * 8) / 2);
        union { unsigned short u[8]; s8v v; } ob;
        deq_pair(pk.x, s, zf, &ob.u[0]);
        deq_pair(pk.y, s, zf, &ob.u[2]);
        deq_pair(pk.z, s, zf, &ob.u[4]);
        deq_pair(pk.w, s, zf, &ob.u[6]);
        *(s8v*)(Bs + unit * 8) = ob.v;
      }
    }
    __syncthreads();

#pragma unroll
    for (int ks = 0; ks < 2; ++ks) {
      bf8 af[4], bfr[4];
#pragma unroll
      for (int mi = 0; mi < 4; ++mi) {
        int row = wm + mi * 16 + lrow;
        int unit = row * 8 + ((ks * 4 + quad) ^ sw);
        af[mi] = *reinterpret_cast<const bf8*>(&As[unit * 8]);
      }
#pragma unroll
      for (int ni = 0; ni < 4; ++ni) {
        int row = wn + ni * 16 + lrow;
        int unit = row * 8 + ((ks * 4 + quad) ^ sw);
        bfr[ni] = *reinterpret_cast<const bf8*>(&Bs[unit * 8]);
      }
#pragma unroll
      for (int mi = 0; mi < 4; ++mi)
#pragma unroll
        for (int ni = 0; ni < 4; ++ni)
          acc[mi][ni] = __builtin_amdgcn_mfma_f32_16x16x32_bf16(
              af[mi], bfr[ni], acc[mi][ni], 0, 0, 0);
    }
  }

  // epilogue: C/D layout col=lane&15 (n), row=quad*4+reg (m)  [m89-verified]
#pragma unroll
  for (int mi = 0; mi < 4; ++mi) {
#pragma unroll
    for (int r = 0; r < 4; ++r) {
      int m = m0 + wm + mi * 16 + quad * 4 + r;
      float* crow = C + (size_t)m * N_OUT + n0 + wn + lrow;
#pragma unroll
      for (int ni = 0; ni < 4; ++ni) crow[ni * 16] = acc[mi][ni][r];
    }
  }
}

extern "C" void kernel_launch(void* const* d_in, const int* in_sizes, int n_in,
                              void* d_out, int out_size, void* d_ws, size_t ws_size,
                              hipStream_t stream) {
  const float* x   = (const float*)d_in[0];
  const int*   wp  = (const int*)d_in[1];
  const float* wsc = (const float*)d_in[2];
  const int*   wz  = (const int*)d_in[3];
  float* out = (float*)d_out;

  const size_t needA = (size_t)M_TOK * K_IN * sizeof(unsigned short);  // 32 MiB
  const size_t needB = (size_t)N_OUT * K_IN * sizeof(unsigned short);  // 86 MiB
  dim3 grid(N_OUT / 128, M_TOK / 128);

  if (ws_size >= needA + needB) {
    unsigned short* Ab = (unsigned short*)d_ws;
    unsigned short* Bb = (unsigned short*)((char*)d_ws + needA);
    cvt_x_kernel<<<(M_TOK * (size_t)K_IN) / (8 * 256), 256, 0, stream>>>(x, Ab);
    deq_w_kernel<<<((size_t)N_OUT * K_IN) / (8 * 256), 256, 0, stream>>>(wp, wsc, wz, Bb);
    gemm_kernel<true><<<grid, 256, 0, stream>>>(Ab, Bb, nullptr, nullptr, nullptr, nullptr, out);
  } else {
    gemm_kernel<false><<<grid, 256, 0, stream>>>(nullptr, nullptr, x, wp, wsc, wz, out);
  }
}